// Round 3
// baseline (34.789 us; speedup 1.0000x reference)
//
#include <hip/hip_runtime.h>
#include <hip/hip_bf16.h>

using floatx4 = __attribute__((ext_vector_type(4))) float;
using shortx8 = __attribute__((ext_vector_type(8))) short;

constexpr int M = 32, N = 4096, K = 4096;
constexpr int WKC = 128;          // k per wave
constexpr int NIT = WKC / 32;     // 4 k-steps, fully preloaded
constexpr int BKC = 4 * WKC;      // 512 k per block (4 waves)
constexpr int SLICES = K / BKC;   // 8 partial slices

// ---- init: out = bias, x -> bf16 (used by both paths; out-init needed only by fallback)
__global__ __launch_bounds__(256) void init_kernel(
    const float* __restrict__ x, const float* __restrict__ bias,
    float* __restrict__ out, short* __restrict__ xbf)
{
    int i = blockIdx.x * blockDim.x + threadIdx.x;
    if (i < M * N) out[i] = bias[i & (N - 1)];
    if (i < M * K) {
        __hip_bfloat16 h = __float2bfloat16(x[i]);
        xbf[i] = *reinterpret_cast<short*>(&h);
    }
}

// ---- main path: no atomics. Block = 16 o-rows x 512 k (4 waves x 128k),
// LDS cross-wave reduce, plain stores to partial[slice]. Inner loop == round-2.
__global__ __launch_bounds__(256) void gemm_p(
    const float* __restrict__ W, const float* __restrict__ scales,
    const short* __restrict__ xbf, const float* __restrict__ tscale,
    float* __restrict__ partial)
{
    const int lane = threadIdx.x & 63;
    const int wave = threadIdx.x >> 6;
    const int o0 = blockIdx.x * 16;
    const int k0 = blockIdx.y * BKC + wave * WKC;

    const int row = lane & 15;
    const int kg  = lane >> 4;

    const float* wp  = W + (size_t)(o0 + row) * K + k0 + kg * 8;
    const float* sp  = scales + (size_t)(o0 + row) * (K / 16) + (k0 >> 4) + (kg >> 1);
    const short* xp0 = xbf + (size_t)row * K + k0 + kg * 8;
    const short* xp1 = xbf + (size_t)(row + 16) * K + k0 + kg * 8;

    // ---- issue ALL global loads up front ----
    floatx4 w0[NIT], w1[NIT];
    #pragma unroll
    for (int i = 0; i < NIT; ++i) {
        w0[i] = *reinterpret_cast<const floatx4*>(wp + i * 32);
        w1[i] = *reinterpret_cast<const floatx4*>(wp + i * 32 + 4);
    }
    float s[NIT];
    #pragma unroll
    for (int i = 0; i < NIT; ++i) s[i] = sp[2 * i];
    shortx8 xa[NIT], xb[NIT];
    #pragma unroll
    for (int i = 0; i < NIT; ++i) {
        xa[i] = *reinterpret_cast<const shortx8*>(xp0 + i * 32);
        xb[i] = *reinterpret_cast<const shortx8*>(xp1 + i * 32);
    }
    const float rt = 1.0f / tscale[0];

    floatx4 acc0 = {0.f, 0.f, 0.f, 0.f};
    floatx4 acc1 = {0.f, 0.f, 0.f, 0.f};

    #pragma unroll
    for (int i = 0; i < NIT; ++i) {
        const float rs = rt / s[i];          // w/(s*t) == w * (rt/s)
        shortx8 wf;
        float wv[8] = {w0[i][0], w0[i][1], w0[i][2], w0[i][3],
                       w1[i][0], w1[i][1], w1[i][2], w1[i][3]};
        #pragma unroll
        for (int j = 0; j < 8; ++j) {
            __hip_bfloat16 h = __float2bfloat16(wv[j] * rs);
            wf[j] = *reinterpret_cast<short*>(&h);
        }
        acc0 = __builtin_amdgcn_mfma_f32_16x16x32_bf16(xa[i], wf, acc0, 0, 0, 0);
        acc1 = __builtin_amdgcn_mfma_f32_16x16x32_bf16(xb[i], wf, acc1, 0, 0, 0);
    }

    // ---- cross-wave reduce in LDS, then ONE plain store per output per block ----
    // acc0[r]: batch b = kg*4+r, o = o0+row ; acc1[r]: b = 16+kg*4+r
    __shared__ float red[4][8][64];
    #pragma unroll
    for (int r = 0; r < 4; ++r) {
        red[wave][r][lane]     = acc0[r];
        red[wave][4 + r][lane] = acc1[r];
    }
    __syncthreads();

    #pragma unroll
    for (int half = 0; half < 2; ++half) {
        int idx = threadIdx.x + half * 256;   // 0..511 = b*16 + oc
        int b = idx >> 4, oc = idx & 15;
        int hi  = b >> 4;                     // acc0 vs acc1
        int kgq = (b >> 2) & 3, r = b & 3;
        int e  = hi * 4 + r;
        int ls = kgq * 16 + oc;
        float v = red[0][e][ls] + red[1][e][ls] + red[2][e][ls] + red[3][e][ls];
        partial[(size_t)blockIdx.y * (M * N) + (size_t)b * N + o0 + oc] = v;
    }
}

// ---- final: out = sum(partials) + bias
__global__ __launch_bounds__(256) void reduce_kernel(
    const float* __restrict__ partial, const float* __restrict__ bias,
    float* __restrict__ out)
{
    int i4 = blockIdx.x * blockDim.x + threadIdx.x;   // float4 index, M*N/4 total
    int o4 = i4 & (N / 4 - 1);
    floatx4 acc = reinterpret_cast<const floatx4*>(bias)[o4];
    #pragma unroll
    for (int s = 0; s < SLICES; ++s)
        acc += reinterpret_cast<const floatx4*>(partial)[(size_t)s * (M * N / 4) + i4];
    reinterpret_cast<floatx4*>(out)[i4] = acc;
}

// ---- fallback (tiny ws): round-2 atomic path, x as f32
__global__ __launch_bounds__(256) void gemm_atomic(
    const float* __restrict__ W, const float* __restrict__ scales,
    const float* __restrict__ xf32, const float* __restrict__ tscale,
    float* __restrict__ out)
{
    const int lane = threadIdx.x & 63;
    const int wave = threadIdx.x >> 6;
    const int o0 = blockIdx.x * 64 + wave * 16;
    const int k0 = blockIdx.y * WKC;
    const int row = lane & 15, kg = lane >> 4;

    const float* wp  = W + (size_t)(o0 + row) * K + k0 + kg * 8;
    const float* sp  = scales + (size_t)(o0 + row) * (K / 16) + (k0 >> 4) + (kg >> 1);
    const float* xf0 = xf32 + (size_t)row * K + k0 + kg * 8;
    const float* xf1 = xf32 + (size_t)(row + 16) * K + k0 + kg * 8;
    const float rt = 1.0f / tscale[0];

    floatx4 acc0 = {0.f, 0.f, 0.f, 0.f};
    floatx4 acc1 = {0.f, 0.f, 0.f, 0.f};
    for (int i = 0; i < NIT; ++i) {
        floatx4 w0 = *reinterpret_cast<const floatx4*>(wp + i * 32);
        floatx4 w1 = *reinterpret_cast<const floatx4*>(wp + i * 32 + 4);
        float s = sp[2 * i];
        shortx8 xa, xb, wf;
        float av[8] = {xf0[i*32+0], xf0[i*32+1], xf0[i*32+2], xf0[i*32+3],
                       xf0[i*32+4], xf0[i*32+5], xf0[i*32+6], xf0[i*32+7]};
        float bv[8] = {xf1[i*32+0], xf1[i*32+1], xf1[i*32+2], xf1[i*32+3],
                       xf1[i*32+4], xf1[i*32+5], xf1[i*32+6], xf1[i*32+7]};
        float wv[8] = {w0[0],w0[1],w0[2],w0[3],w1[0],w1[1],w1[2],w1[3]};
        const float rs = rt / s;
        #pragma unroll
        for (int j = 0; j < 8; ++j) {
            __hip_bfloat16 ha = __float2bfloat16(av[j]);
            __hip_bfloat16 hb = __float2bfloat16(bv[j]);
            __hip_bfloat16 hw = __float2bfloat16(wv[j] * rs);
            xa[j] = *reinterpret_cast<short*>(&ha);
            xb[j] = *reinterpret_cast<short*>(&hb);
            wf[j] = *reinterpret_cast<short*>(&hw);
        }
        acc0 = __builtin_amdgcn_mfma_f32_16x16x32_bf16(xa, wf, acc0, 0, 0, 0);
        acc1 = __builtin_amdgcn_mfma_f32_16x16x32_bf16(xb, wf, acc1, 0, 0, 0);
    }
    float* op0 = out + (size_t)(kg * 4) * N + o0 + row;
    float* op1 = out + (size_t)(16 + kg * 4) * N + o0 + row;
    #pragma unroll
    for (int r = 0; r < 4; ++r) {
        atomicAdd(op0 + (size_t)r * N, acc0[r]);
        atomicAdd(op1 + (size_t)r * N, acc1[r]);
    }
}

extern "C" void kernel_launch(void* const* d_in, const int* in_sizes, int n_in,
                              void* d_out, int out_size, void* d_ws, size_t ws_size,
                              hipStream_t stream)
{
    const float* x      = (const float*)d_in[0];
    const float* W      = (const float*)d_in[1];
    const float* tscale = (const float*)d_in[2];
    const float* scales = (const float*)d_in[3];
    const float* bias   = (const float*)d_in[4];
    float* out = (float*)d_out;

    const size_t xbf_bytes     = (size_t)M * K * sizeof(short);        // 256 KiB
    const size_t partial_bytes = (size_t)SLICES * M * N * sizeof(float); // 4 MiB

    if (ws_size >= xbf_bytes + partial_bytes) {
        short* xbf     = (short*)d_ws;
        float* partial = (float*)((char*)d_ws + xbf_bytes);

        init_kernel<<<(M * K + 255) / 256, 256, 0, stream>>>(x, bias, out, xbf);
        dim3 grid(N / 16, SLICES);
        gemm_p<<<grid, 256, 0, stream>>>(W, scales, xbf, tscale, partial);
        reduce_kernel<<<(M * N / 4 + 255) / 256, 256, 0, stream>>>(partial, bias, out);
    } else {
        // fallback: atomic path, x read as f32 (no ws needed beyond none)
        init_kernel<<<(M * K + 255) / 256, 256, 0, stream>>>(x, bias, out, (short*)d_ws);
        dim3 grid(N / 64, K / WKC);
        gemm_atomic<<<grid, 256, 0, stream>>>(W, scales, x, tscale, out);
    }
}

// Round 4
// 29.788 us; speedup vs baseline: 1.1679x; 1.1679x over previous
//
#include <hip/hip_runtime.h>
#include <hip/hip_bf16.h>

using floatx4 = __attribute__((ext_vector_type(4))) float;
using shortx8 = __attribute__((ext_vector_type(8))) short;
using uintx2  = __attribute__((ext_vector_type(2))) unsigned int;

constexpr int M = 32, N = 4096, K = 4096;
constexpr int CHUNK = 128;            // k per chunk
constexpr int NCH = 4;                // chunks per wave
constexpr int WSPAN = CHUNK * NCH;    // 512 k per wave
constexpr int SLICES = K / WSPAN;     // 8 partial slices
constexpr int KS = SLICES / 4;        // grid.y = 2  (4 waves per block)

// ---- init: out = bias (for fallback), x -> bf16
__global__ __launch_bounds__(256) void init_kernel(
    const float* __restrict__ x, const float* __restrict__ bias,
    float* __restrict__ out, short* __restrict__ xbf)
{
    int i = blockIdx.x * blockDim.x + threadIdx.x;
    if (i < M * N) out[i] = bias[i & (N - 1)];
    if (i < M * K) {
        __hip_bfloat16 h = __float2bfloat16(x[i]);
        xbf[i] = *reinterpret_cast<short*>(&h);
    }
}

__device__ __forceinline__ unsigned int pk_bf16(float a, float b) {
    __hip_bfloat16 ha = __float2bfloat16(a), hb = __float2bfloat16(b);
    return (unsigned int)*reinterpret_cast<unsigned short*>(&ha) |
           ((unsigned int)*reinterpret_cast<unsigned short*>(&hb) << 16);
}

// ---- main: linear W loads -> reg dequant -> swizzled wave-private LDS -> MFMA.
// No barriers, no atomics. Wave = 16 o-rows x 512 k (4 chunks of 128).
__global__ __launch_bounds__(256, 2) void gemm_lds(
    const float* __restrict__ W, const float* __restrict__ scales,
    const short* __restrict__ xbf, const float* __restrict__ tscale,
    float* __restrict__ partial)
{
    __shared__ short lds_buf[4 * NCH * 2048];   // 4 waves * 4 chunks * 4KB = 64KB

    const int lane = threadIdx.x & 63;
    const int wave = threadIdx.x >> 6;
    const int o0  = blockIdx.x * 16;
    const int kw0 = blockIdx.y * (WSPAN * 4) + wave * WSPAN;

    // staging lane mapping: 2 rows per instr, 512B contiguous per row
    const int srow = lane >> 5;          // row within pair
    const int c4   = lane & 31;          // 16B column index (4 floats)
    // fragment lane mapping
    const int frow = lane & 15;
    const int kg   = lane >> 4;

    const float rt = 1.0f / tscale[0];

    floatx4 w[2][8]; float sc[2][8];
    shortx8 xa[2][4], xb[2][4];

    auto loadW = [&](int c, int sl) {
        const int kc0 = kw0 + c * CHUNK;
        #pragma unroll
        for (int j = 0; j < 8; ++j) {
            const int r = 2 * j + srow;
            w[sl][j] = *reinterpret_cast<const floatx4*>(
                W + (size_t)(o0 + r) * K + kc0 + c4 * 4);
            sc[sl][j] = scales[(size_t)(o0 + r) * (K / 16) + (kc0 >> 4) + (c4 >> 2)];
        }
    };
    auto loadX = [&](int c, int sl) {
        const int kc0 = kw0 + c * CHUNK;
        #pragma unroll
        for (int s = 0; s < 4; ++s) {
            xa[sl][s] = *reinterpret_cast<const shortx8*>(
                xbf + (size_t)frow * K + kc0 + s * 32 + kg * 8);
            xb[sl][s] = *reinterpret_cast<const shortx8*>(
                xbf + (size_t)(frow + 16) * K + kc0 + s * 32 + kg * 8);
        }
    };

    loadW(0, 0);
    loadW(1, 1);
    loadX(0, 0);

    floatx4 acc0 = {0.f, 0.f, 0.f, 0.f};
    floatx4 acc1 = {0.f, 0.f, 0.f, 0.f};
    short* mybuf = &lds_buf[wave * (NCH * 2048)];

    #pragma unroll
    for (int c = 0; c < NCH; ++c) {
        const int sl = c & 1;
        if (c + 1 < NCH) loadX(c + 1, (c + 1) & 1);

        // dequant + swizzled LDS write of chunk c (wave-private buffer)
        short* buf = mybuf + c * 2048;
        #pragma unroll
        for (int j = 0; j < 8; ++j) {
            const int r = 2 * j + srow;
            const float rs = rt * __builtin_amdgcn_rcpf(sc[sl][j]);
            uintx2 pv = { pk_bf16(w[sl][j][0] * rs, w[sl][j][1] * rs),
                          pk_bf16(w[sl][j][2] * rs, w[sl][j][3] * rs) };
            // 16B slot = k/8, swizzled by XOR row; 8B sub-slot = c4&1
            *reinterpret_cast<uintx2*>(
                buf + r * 128 + (((c4 >> 1) ^ r) & 15) * 8 + (c4 & 1) * 4) = pv;
        }

        if (c + 2 < NCH) loadW(c + 2, sl);   // prefetch depth 2

        // compute chunk c: 4 k-steps, 1 swizzled ds_read_b128 + 2 MFMA each
        #pragma unroll
        for (int s = 0; s < 4; ++s) {
            shortx8 wf = *reinterpret_cast<const shortx8*>(
                buf + frow * 128 + (((kg + 4 * s) ^ frow) & 15) * 8);
            acc0 = __builtin_amdgcn_mfma_f32_16x16x32_bf16(xa[sl][s], wf, acc0, 0, 0, 0);
            acc1 = __builtin_amdgcn_mfma_f32_16x16x32_bf16(xb[sl][s], wf, acc1, 0, 0, 0);
        }
    }

    // wave-private partial slice store (no atomics, no cross-wave reduce)
    const int slice = blockIdx.y * 4 + wave;
    float* pp = partial + (size_t)slice * (M * N);
    #pragma unroll
    for (int r = 0; r < 4; ++r) {
        pp[(size_t)(kg * 4 + r) * N + o0 + frow]      = acc0[r];
        pp[(size_t)(16 + kg * 4 + r) * N + o0 + frow] = acc1[r];
    }
}

// ---- final: out = sum(partials) + bias
__global__ __launch_bounds__(256) void reduce_kernel(
    const float* __restrict__ partial, const float* __restrict__ bias,
    float* __restrict__ out)
{
    int i4 = blockIdx.x * blockDim.x + threadIdx.x;   // float4 index, M*N/4 total
    int o4 = i4 & (N / 4 - 1);
    floatx4 acc = reinterpret_cast<const floatx4*>(bias)[o4];
    #pragma unroll
    for (int s = 0; s < SLICES; ++s)
        acc += reinterpret_cast<const floatx4*>(partial)[(size_t)s * (M * N / 4) + i4];
    reinterpret_cast<floatx4*>(out)[i4] = acc;
}

// ---- fallback (tiny ws): atomic path, x as f32
__global__ __launch_bounds__(256) void gemm_atomic(
    const float* __restrict__ W, const float* __restrict__ scales,
    const float* __restrict__ xf32, const float* __restrict__ tscale,
    float* __restrict__ out)
{
    const int lane = threadIdx.x & 63;
    const int wave = threadIdx.x >> 6;
    const int o0 = blockIdx.x * 64 + wave * 16;
    const int k0 = blockIdx.y * CHUNK;
    const int row = lane & 15, kg = lane >> 4;

    const float* wp  = W + (size_t)(o0 + row) * K + k0 + kg * 8;
    const float* sp  = scales + (size_t)(o0 + row) * (K / 16) + (k0 >> 4) + (kg >> 1);
    const float* xf0 = xf32 + (size_t)row * K + k0 + kg * 8;
    const float* xf1 = xf32 + (size_t)(row + 16) * K + k0 + kg * 8;
    const float rt = 1.0f / tscale[0];

    floatx4 acc0 = {0.f, 0.f, 0.f, 0.f};
    floatx4 acc1 = {0.f, 0.f, 0.f, 0.f};
    for (int i = 0; i < CHUNK / 32; ++i) {
        floatx4 w0 = *reinterpret_cast<const floatx4*>(wp + i * 32);
        floatx4 w1 = *reinterpret_cast<const floatx4*>(wp + i * 32 + 4);
        float s = sp[2 * i];
        shortx8 xav, xbv, wf;
        const float rs = rt / s;
        float av[8] = {xf0[i*32+0], xf0[i*32+1], xf0[i*32+2], xf0[i*32+3],
                       xf0[i*32+4], xf0[i*32+5], xf0[i*32+6], xf0[i*32+7]};
        float bv[8] = {xf1[i*32+0], xf1[i*32+1], xf1[i*32+2], xf1[i*32+3],
                       xf1[i*32+4], xf1[i*32+5], xf1[i*32+6], xf1[i*32+7]};
        float wv[8] = {w0[0],w0[1],w0[2],w0[3],w1[0],w1[1],w1[2],w1[3]};
        #pragma unroll
        for (int j = 0; j < 8; ++j) {
            __hip_bfloat16 ha = __float2bfloat16(av[j]);
            __hip_bfloat16 hb = __float2bfloat16(bv[j]);
            __hip_bfloat16 hw = __float2bfloat16(wv[j] * rs);
            xav[j] = *reinterpret_cast<short*>(&ha);
            xbv[j] = *reinterpret_cast<short*>(&hb);
            wf[j]  = *reinterpret_cast<short*>(&hw);
        }
        acc0 = __builtin_amdgcn_mfma_f32_16x16x32_bf16(xav, wf, acc0, 0, 0, 0);
        acc1 = __builtin_amdgcn_mfma_f32_16x16x32_bf16(xbv, wf, acc1, 0, 0, 0);
    }
    float* op0 = out + (size_t)(kg * 4) * N + o0 + row;
    float* op1 = out + (size_t)(16 + kg * 4) * N + o0 + row;
    #pragma unroll
    for (int r = 0; r < 4; ++r) {
        atomicAdd(op0 + (size_t)r * N, acc0[r]);
        atomicAdd(op1 + (size_t)r * N, acc1[r]);
    }
}

extern "C" void kernel_launch(void* const* d_in, const int* in_sizes, int n_in,
                              void* d_out, int out_size, void* d_ws, size_t ws_size,
                              hipStream_t stream)
{
    const float* x      = (const float*)d_in[0];
    const float* W      = (const float*)d_in[1];
    const float* tscale = (const float*)d_in[2];
    const float* scales = (const float*)d_in[3];
    const float* bias   = (const float*)d_in[4];
    float* out = (float*)d_out;

    const size_t xbf_bytes     = (size_t)M * K * sizeof(short);          // 256 KiB
    const size_t partial_bytes = (size_t)SLICES * M * N * sizeof(float); // 4 MiB

    if (ws_size >= xbf_bytes + partial_bytes) {
        short* xbf     = (short*)d_ws;
        float* partial = (float*)((char*)d_ws + xbf_bytes);

        init_kernel<<<(M * K + 255) / 256, 256, 0, stream>>>(x, bias, out, xbf);
        dim3 grid(N / 16, KS);
        gemm_lds<<<grid, 256, 0, stream>>>(W, scales, xbf, tscale, partial);
        reduce_kernel<<<(M * N / 4 + 255) / 256, 256, 0, stream>>>(partial, bias, out);
    } else {
        init_kernel<<<(M * K + 255) / 256, 256, 0, stream>>>(x, bias, out, (short*)d_ws);
        dim3 grid(N / 64, K / CHUNK);
        gemm_atomic<<<grid, 256, 0, stream>>>(W, scales, x, tscale, out);
    }
}